// Round 3
// baseline (177.256 us; speedup 1.0000x reference)
//
#include <hip/hip_runtime.h>

// y[b,c,0] = x[b,c,0];  y[b,c,n] = 0.3*x[n] + 0.7*y[n-1]  along axis 2 (N=32)
// Shapes: [4, 3, 32, 256, 256] fp32.
//
// R1/R2 lesson: with default occupancy targets the AMDGPU scheduler sinks
// batched loads back to their uses (VGPR stayed 28-32, 1 load in flight,
// 2.2 TB/s, latency-bound). Fix: __launch_bounds__(256,1) lifts the VGPR
// pressure target to ~512 so holding all 32 frames (128 VGPRs) is free, and
// sched_barrier(0) pins loads above the compute/store region.
// Occupancy is grid-limited (768 blocks = 3 blocks/CU = 12 waves/CU) as long
// as VGPR <= 168; one wave then has 32 KB of loads in flight >> ~12 KB/CU
// needed to saturate HBM.

constexpr int   BC  = 4 * 3;
constexpr int   NFR = 32;
constexpr int   HW4 = (256 * 256) / 4;   // float4 per frame-plane = 16384
constexpr float WF  = 0.3f;
constexpr float OMW = 1.0f - WF;

__global__ __launch_bounds__(256, 1) void recfilt_kernel(const float4* __restrict__ x,
                                                         float4* __restrict__ y) {
    const int p  = blockIdx.x * blockDim.x + threadIdx.x;
    const int bc = p >> 14;              // / HW4
    const int hw = p & (HW4 - 1);        // % HW4
    const long base = (long)bc * NFR * HW4 + hw;

    // Issue ALL 32 independent loads before any dependent use.
    float4 v[NFR];
#pragma unroll
    for (int n = 0; n < NFR; ++n)
        v[n] = x[base + (long)n * HW4];

    // Nothing (esp. the loads above) may be moved across this point.
    __builtin_amdgcn_sched_barrier(0);

    // Dependent recurrence, in place: v[n] becomes y[n].
#pragma unroll
    for (int n = 1; n < NFR; ++n) {
        v[n].x = WF * v[n].x + OMW * v[n - 1].x;
        v[n].y = WF * v[n].y + OMW * v[n - 1].y;
        v[n].z = WF * v[n].z + OMW * v[n - 1].z;
        v[n].w = WF * v[n].w + OMW * v[n - 1].w;
    }

    // Drain the write stream.
#pragma unroll
    for (int n = 0; n < NFR; ++n)
        y[base + (long)n * HW4] = v[n];
}

extern "C" void kernel_launch(void* const* d_in, const int* in_sizes, int n_in,
                              void* d_out, int out_size, void* d_ws, size_t ws_size,
                              hipStream_t stream) {
    const float4* x = (const float4*)d_in[0];
    float4*       y = (float4*)d_out;
    const int chains = BC * HW4;              // 196,608 threads
    const int block  = 256;
    const int grid   = chains / block;        // 768 blocks
    recfilt_kernel<<<grid, block, 0, stream>>>(x, y);
}